// Round 1
// 782.840 us; speedup vs baseline: 1.1518x; 1.1518x over previous
//
#include <hip/hip_runtime.h>
#include <cstdint>

typedef __bf16 bf16_t;
typedef __attribute__((ext_vector_type(8))) __bf16 bf16x8;
typedef __attribute__((ext_vector_type(4))) __bf16 bf16x4;
typedef __attribute__((ext_vector_type(4))) float f32x4;

typedef __attribute__((address_space(1))) void void_g;
typedef __attribute__((address_space(3))) void void_l;

#define GLDS16(gp, lp) __builtin_amdgcn_global_load_lds( \
    (void_g*)(uintptr_t)(gp), (void_l*)(uintptr_t)(lp), 16, 0, 0)

constexpr int Bc = 4, Sc = 1024, Hc = 32, KVHc = 8, HDc = 128, DMc = 4096;
constexpr int NQ = 6144;     // q|k|v concatenated width
constexpr int WINc = 512;

// ---------------- cast hidden fp32 -> bf16 (vectorized) ----------------
__global__ void cast_kernel(const float* __restrict__ in, bf16_t* __restrict__ out, int n4) {
    int i = blockIdx.x * blockDim.x + threadIdx.x;
    if (i >= n4) return;
    float4 v = reinterpret_cast<const float4*>(in)[i];
    bf16x4 o;
    o[0] = (bf16_t)v.x; o[1] = (bf16_t)v.y; o[2] = (bf16_t)v.z; o[3] = (bf16_t)v.w;
    reinterpret_cast<bf16x4*>(out)[i] = o;
}

// ---------------- cast+transpose: in fp32 [R][C] -> out bf16 [C][R] ----------------
__global__ void transpose_cast(const float* __restrict__ in, bf16_t* __restrict__ out,
                               int R, int C) {
    __shared__ float tile[32][33];
    int c0 = blockIdx.x * 32, r0 = blockIdx.y * 32;
    int tx = threadIdx.x, ty = threadIdx.y;   // (32,8)
    for (int i = 0; i < 32; i += 8)
        tile[ty + i][tx] = in[(size_t)(r0 + ty + i) * C + c0 + tx];
    __syncthreads();
    for (int i = 0; i < 32; i += 8)
        out[(size_t)(c0 + ty + i) * R + r0 + tx] = (bf16_t)tile[tx][ty + i];
}

// ---------------- bf16 MFMA GEMM: C[M][N] = A[M][K] * BT[N][K]^T ----------------
// 256x128 tile, BK=64 in two ks=32 groups, 8 waves (2M x 4N), per-wave 128x32.
// Counted-vmcnt pipeline (T3+T4): stages of tile t+1 issued during tile t's
// groups; vmcnt(3) at each group boundary keeps one ks-half (3 loads/wave) in
// flight across every barrier; never drains to 0 until the peeled last tile.
// LDS is k-split-major so each ks-half is a contiguous, independently-staged
// region; granule swizzle g = slot ^ ((row>>1)&3) on BOTH source and read.
template <typename CT>
__global__ __launch_bounds__(512, 2) void gemm256(const bf16_t* __restrict__ A,
                                                  const bf16_t* __restrict__ BT,
                                                  CT* __restrict__ C,
                                                  int M, int N, int K) {
    __shared__ bf16_t As[2 * 2 * 256 * 32];   // [buf][ks][row 256][col 32] = 64 KiB
    __shared__ bf16_t Bs[2 * 2 * 128 * 32];   // [buf][ks][row 128][col 32] = 32 KiB

    const int t = threadIdx.x;
    const int lane = t & 63, w = t >> 6;
    const int wm = w >> 2, wn = w & 3;
    const int l15 = lane & 15, quad = lane >> 4;

    // group-major block remap: 8 consecutive M-tiles per N sweep (L2 locality)
    const int pid = blockIdx.y * gridDim.x + blockIdx.x;
    const int npn = gridDim.x, npm = gridDim.y;
    const int gsz = 8 * npn;
    const int grp = pid / gsz;
    const int first = grp * 8;
    const int gs = (npm - first) < 8 ? (npm - first) : 8;
    const int pm = first + (pid % gs);
    const int pn = (pid % gsz) / gs;
    const int mBase = pm * 256, nBase = pn * 128;

    // ---- staging source addresses (per lane; inverse-swizzled global src) ----
    const int r_in = lane >> 2;          // row within a 16-row wave granule
    const int sl = lane & 3;             // 16B slot within the 64B LDS row
    const int g = sl ^ ((r_in >> 1) & 3);
    const bf16_t* srcA0 = A + (size_t)(mBase + w * 16 + r_in) * K + g * 8;
    const bf16_t* srcA1 = srcA0 + (size_t)128 * K;
    const bf16_t* srcB0 = BT + (size_t)(nBase + w * 16 + r_in) * K + g * 8;

    // ---- LDS read bases (per lane; matching swizzle) ----
    const int rsw = (quad ^ ((l15 >> 1) & 3)) * 8;
    const int aoff = (wm * 128 + l15) * 32 + rsw;
    const int boff = (wn * 32 + l15) * 32 + rsw;

    f32x4 acc[8][2] = {};
    const int NT = K >> 6;

    // prologue: stage tile 0 into buf 0 (order ks0{B,A,A}, ks1{B,A,A})
    GLDS16(srcB0,      &Bs[(0 * 128 + w * 16) * 32]);
    GLDS16(srcA0,      &As[(0 * 256 + w * 16) * 32]);
    GLDS16(srcA1,      &As[(0 * 256 + 128 + w * 16) * 32]);
    GLDS16(srcB0 + 32, &Bs[(1 * 128 + w * 16) * 32]);
    GLDS16(srcA0 + 32, &As[(1 * 256 + w * 16) * 32]);
    GLDS16(srcA1 + 32, &As[(1 * 256 + 128 + w * 16) * 32]);

    for (int ti = 0; ti < NT - 1; ++ti) {
        const int buf = ti & 1, nbuf = buf ^ 1;
        const size_t kk = (size_t)(ti + 1) * 64;
#pragma unroll
        for (int ks = 0; ks < 2; ks++) {
            // boundary: my ks-half stages for tile ti are retired; one half in flight
            asm volatile("s_waitcnt vmcnt(3)" ::: "memory");
            __builtin_amdgcn_s_barrier();
            // stage ks-half of tile ti+1 into nbuf (its last reads ended 2 groups ago)
            GLDS16(srcB0 + kk + ks * 32, &Bs[((nbuf * 2 + ks) * 128 + w * 16) * 32]);
            GLDS16(srcA0 + kk + ks * 32, &As[((nbuf * 2 + ks) * 256 + w * 16) * 32]);
            GLDS16(srcA1 + kk + ks * 32, &As[((nbuf * 2 + ks) * 256 + 128 + w * 16) * 32]);
            // fragments from buf
            bf16x8 af[8], bv[2];
            const bf16_t* Ab = &As[(buf * 2 + ks) * 8192 + aoff];
            const bf16_t* Bb = &Bs[(buf * 2 + ks) * 4096 + boff];
#pragma unroll
            for (int mf = 0; mf < 8; mf++)
                af[mf] = *reinterpret_cast<const bf16x8*>(Ab + mf * 512);
#pragma unroll
            for (int nf = 0; nf < 2; nf++)
                bv[nf] = *reinterpret_cast<const bf16x8*>(Bb + nf * 512);
            __builtin_amdgcn_s_setprio(1);
#pragma unroll
            for (int mf = 0; mf < 8; mf++)
#pragma unroll
                for (int nf = 0; nf < 2; nf++)
                    acc[mf][nf] = __builtin_amdgcn_mfma_f32_16x16x32_bf16(af[mf], bv[nf], acc[mf][nf], 0, 0, 0);
            __builtin_amdgcn_s_setprio(0);
        }
    }
    // peeled last tile: no stages; second group drains fully
    {
        const int buf = (NT - 1) & 1;
#pragma unroll
        for (int ks = 0; ks < 2; ks++) {
            if (ks == 0) { asm volatile("s_waitcnt vmcnt(3)" ::: "memory"); }
            else         { asm volatile("s_waitcnt vmcnt(0)" ::: "memory"); }
            __builtin_amdgcn_s_barrier();
            bf16x8 af[8], bv[2];
            const bf16_t* Ab = &As[(buf * 2 + ks) * 8192 + aoff];
            const bf16_t* Bb = &Bs[(buf * 2 + ks) * 4096 + boff];
#pragma unroll
            for (int mf = 0; mf < 8; mf++)
                af[mf] = *reinterpret_cast<const bf16x8*>(Ab + mf * 512);
#pragma unroll
            for (int nf = 0; nf < 2; nf++)
                bv[nf] = *reinterpret_cast<const bf16x8*>(Bb + nf * 512);
            __builtin_amdgcn_s_setprio(1);
#pragma unroll
            for (int mf = 0; mf < 8; mf++)
#pragma unroll
                for (int nf = 0; nf < 2; nf++)
                    acc[mf][nf] = __builtin_amdgcn_mfma_f32_16x16x32_bf16(af[mf], bv[nf], acc[mf][nf], 0, 0, 0);
            __builtin_amdgcn_s_setprio(0);
        }
    }
    // epilogue
#pragma unroll
    for (int mf = 0; mf < 8; mf++) {
        const int row0 = mBase + wm * 128 + mf * 16 + quad * 4;
#pragma unroll
        for (int nf = 0; nf < 2; nf++) {
            const int col = nBase + wn * 32 + nf * 16 + l15;
#pragma unroll
            for (int r = 0; r < 4; r++)
                C[(size_t)(row0 + r) * N + col] = (CT)acc[mf][nf][r];
        }
    }
}

// ---------------- RoPE: qkv bf16 [4096][6144] -> Qo [4096][4096], Ko [4096][1024] ----------------
__global__ void rope_kernel(const bf16_t* __restrict__ qkv, const int* __restrict__ pos,
                            bf16_t* __restrict__ Qo, bf16_t* __restrict__ Ko) {
    int t = blockIdx.y;
    int hd = blockIdx.x * blockDim.x + threadIdx.x;  // 0..2559 (40 heads x 64 pairs)
    int head = hd >> 6, d = hd & 63;
    float p = (float)pos[t];
    float invf = exp2f(-(float)d * (19.931568569324174f / 64.0f));
    float ang = p * invf;
    float sn, cs;
    __sincosf(ang, &sn, &cs);
    const bf16_t* src; bf16_t* dst;
    if (head < 32) {
        src = qkv + (size_t)t * NQ + head * 128 + d;
        dst = Qo + (size_t)t * DMc + head * 128 + d;
    } else {
        int kh = head - 32;
        src = qkv + (size_t)t * NQ + 4096 + kh * 128 + d;
        dst = Ko + (size_t)t * (KVHc * HDc) + kh * 128 + d;
    }
    float x1 = (float)src[0], x2 = (float)src[64];
    dst[0]  = (bf16_t)(x1 * cs - x2 * sn);
    dst[64] = (bf16_t)(x2 * cs + x1 * sn);
}

// ---------------- V transpose: qkv v-part -> Vt [b*KVH][HD][S] ----------------
__global__ void vtrans_kernel(const bf16_t* __restrict__ qkv, bf16_t* __restrict__ Vt) {
    __shared__ bf16_t tile[32][33];
    int bh = blockIdx.z;               // b*8+kvh
    int b = bh >> 3, kvh = bh & 7;
    int s0 = blockIdx.x * 32, d0 = blockIdx.y * 32;
    int tx = threadIdx.x, ty = threadIdx.y;  // (32,8)
    for (int i = 0; i < 32; i += 8)
        tile[ty + i][tx] = qkv[(size_t)(b * Sc + s0 + ty + i) * NQ + 5120 + kvh * 128 + d0 + tx];
    __syncthreads();
    for (int i = 0; i < 32; i += 8)
        Vt[((size_t)bh * 128 + d0 + ty + i) * Sc + s0 + tx] = tile[tx][ty + i];
}

// ---------------- attention: 4 waves/block = 4 heads sharing a kvh group ----------------
// K/V tiles staged to LDS (double-buffered, XOR-swizzled), one barrier/step.
__global__ __launch_bounds__(256) void attn_kernel(const bf16_t* __restrict__ Q,
                                                   const bf16_t* __restrict__ Kk,
                                                   const bf16_t* __restrict__ Vt,
                                                   bf16_t* __restrict__ O) {
    __shared__ bf16_t Ks[2][32 * 128];
    __shared__ bf16_t Vs[2][128 * 32];
    __shared__ bf16_t Plds[4][16 * 32];
    const int bid = blockIdx.x;        // b*512 + kvh*64 + qt
    const int qt = bid & 63;
    const int kvh = (bid >> 6) & 7;
    const int b = bid >> 9;
    const int t = threadIdx.x;
    const int lane = t & 63, w = t >> 6;
    const int h = kvh * 4 + w;
    const int l15 = lane & 15, quad = lane >> 4;
    const int qb = qt * 16;

    // per-wave Q fragment (A-layout)
    bf16x8 qf[4];
    const bf16_t* qp = Q + (size_t)(b * Sc + qb + l15) * DMc + h * HDc + quad * 8;
#pragma unroll
    for (int c = 0; c < 4; c++) qf[c] = *reinterpret_cast<const bf16x8*>(qp + c * 32);

    // staging source offsets (per thread; two 16B granules per matrix)
    const int kr0 = t >> 4;                                 // rows 0..15 (second: +16)
    const int kc0 = (((t & 15) ^ (kr0 & 7)) * 8);
    const bf16_t* Kbase = Kk + (size_t)(b * Sc) * (KVHc * HDc) + kvh * HDc;
    const size_t kOff0 = (size_t)kr0 * (KVHc * HDc) + kc0;
    const size_t kOff1 = kOff0 + (size_t)16 * (KVHc * HDc);
    const int vd0 = t >> 2;                                 // d 0..63 (second: +64)
    const int vc0 = (((t & 3) ^ ((vd0 >> 1) & 3)) * 8);
    const bf16_t* Vbase = Vt + (size_t)(b * KVHc + kvh) * HDc * Sc;
    const size_t vOff0 = (size_t)vd0 * Sc + vc0;
    const size_t vOff1 = vOff0 + (size_t)64 * Sc;

    f32x4 oacc[8] = {};
    float m_r[4], l_r[4];
#pragma unroll
    for (int r = 0; r < 4; r++) { m_r[r] = -1e30f; l_r[r] = 0.f; }

    const int swl = (l15 >> 1) & 3;    // V/P read-granule swizzle
    const int swk = l15 & 7;           // K read-granule swizzle

    int lo = qb - (WINc - 1); if (lo < 0) lo = 0;
    const int kv_lo = lo & ~31;
    const int nsteps = (qb + 16 - kv_lo + 31) / 32;

    // prologue stage into buf 0
    {
        const bf16_t* ks = Kbase + (size_t)kv_lo * (KVHc * HDc);
        GLDS16(ks + kOff0, &Ks[0][w * 512]);
        GLDS16(ks + kOff1, &Ks[0][2048 + w * 512]);
        const bf16_t* vs = Vbase + kv_lo;
        GLDS16(vs + vOff0, &Vs[0][w * 512]);
        GLDS16(vs + vOff1, &Vs[0][2048 + w * 512]);
    }

    int buf = 0;
    for (int s = 0; s < nsteps; s++) {
        const int kv = kv_lo + s * 32;
        __syncthreads();   // staging of buf complete; prior reads of buf^1 done
        if (s + 1 < nsteps) {
            const int nb = buf ^ 1;
            const bf16_t* ks = Kbase + (size_t)(kv + 32) * (KVHc * HDc);
            GLDS16(ks + kOff0, &Ks[nb][w * 512]);
            GLDS16(ks + kOff1, &Ks[nb][2048 + w * 512]);
            const bf16_t* vs = Vbase + kv + 32;
            GLDS16(vs + vOff0, &Vs[nb][w * 512]);
            GLDS16(vs + vOff1, &Vs[nb][2048 + w * 512]);
        }
        // QK^T from LDS
        f32x4 s0 = {}, s1 = {};
#pragma unroll
        for (int c = 0; c < 4; c++) {
            bf16x8 kf = *reinterpret_cast<const bf16x8*>(
                &Ks[buf][l15 * 128 + (((c * 4 + quad) ^ swk) * 8)]);
            s0 = __builtin_amdgcn_mfma_f32_16x16x32_bf16(qf[c], kf, s0, 0, 0, 0);
        }
#pragma unroll
        for (int c = 0; c < 4; c++) {
            bf16x8 kf = *reinterpret_cast<const bf16x8*>(
                &Ks[buf][(16 + l15) * 128 + (((c * 4 + quad) ^ swk) * 8)]);
            s1 = __builtin_amdgcn_mfma_f32_16x16x32_bf16(qf[c], kf, s1, 0, 0, 0);
        }
        const float scale = 0.08838834764831845f;  // 1/sqrt(128)
        const bool interior = (kv + 31 <= qb) && (kv >= qb - 496);
        float p0[4], p1[4], alpha[4];
#pragma unroll
        for (int r = 0; r < 4; r++) {
            float v0, v1;
            if (interior) {
                v0 = s0[r] * scale; v1 = s1[r] * scale;
            } else {
                int i = qb + quad * 4 + r;
                int j0 = kv + l15, j1 = j0 + 16;
                v0 = (j0 <= i && j0 > i - WINc) ? s0[r] * scale : -1e30f;
                v1 = (j1 <= i && j1 > i - WINc) ? s1[r] * scale : -1e30f;
            }
            float mx = fmaxf(v0, v1);
            mx = fmaxf(mx, __shfl_xor(mx, 1));
            mx = fmaxf(mx, __shfl_xor(mx, 2));
            mx = fmaxf(mx, __shfl_xor(mx, 4));
            mx = fmaxf(mx, __shfl_xor(mx, 8));
            float mnew = fmaxf(m_r[r], mx);
            alpha[r] = __expf(m_r[r] - mnew);
            m_r[r] = mnew;
            p0[r] = __expf(v0 - mnew);
            p1[r] = __expf(v1 - mnew);
            float rs = p0[r] + p1[r];
            rs += __shfl_xor(rs, 1);
            rs += __shfl_xor(rs, 2);
            rs += __shfl_xor(rs, 4);
            rs += __shfl_xor(rs, 8);
            l_r[r] = l_r[r] * alpha[r] + rs;
        }
#pragma unroll
        for (int c = 0; c < 8; c++)
#pragma unroll
            for (int r = 0; r < 4; r++)
                oacc[c][r] *= alpha[r];
        // P: C-layout -> LDS (swizzled) -> A-layout fragment (wave-local ordering
        // via compiler-inserted lgkmcnt; no barrier so prefetch stays in flight)
#pragma unroll
        for (int r = 0; r < 4; r++) {
            int row = quad * 4 + r;
            int sw = (row >> 1) & 3;
            int g0 = l15 >> 3, g1 = 2 + (l15 >> 3);
            Plds[w][row * 32 + (((g0 ^ sw) << 3) | (l15 & 7))] = (bf16_t)p0[r];
            Plds[w][row * 32 + (((g1 ^ sw) << 3) | (l15 & 7))] = (bf16_t)p1[r];
        }
        bf16x8 pf = *reinterpret_cast<const bf16x8*>(&Plds[w][l15 * 32 + ((quad ^ swl) * 8)]);
#pragma unroll
        for (int c = 0; c < 8; c++) {
            bf16x8 vf = *reinterpret_cast<const bf16x8*>(
                &Vs[buf][(c * 16 + l15) * 32 + ((quad ^ swl) * 8)]);
            oacc[c] = __builtin_amdgcn_mfma_f32_16x16x32_bf16(pf, vf, oacc[c], 0, 0, 0);
        }
        buf ^= 1;
    }
    bf16_t* op = O + (size_t)(b * Sc + qb) * DMc + h * HDc;
#pragma unroll
    for (int r = 0; r < 4; r++) {
        float inv = 1.0f / l_r[r];
        int row = quad * 4 + r;
#pragma unroll
        for (int c = 0; c < 8; c++)
            op[(size_t)row * DMc + c * 16 + l15] = (bf16_t)(oacc[c][r] * inv);
    }
}

extern "C" void kernel_launch(void* const* d_in, const int* in_sizes, int n_in,
                              void* d_out, int out_size, void* d_ws, size_t ws_size,
                              hipStream_t stream) {
    const float* hidden = (const float*)d_in[0];
    const float* Wq = (const float*)d_in[1];
    const float* Wk = (const float*)d_in[2];
    const float* Wv = (const float*)d_in[3];
    const float* Wo = (const float*)d_in[4];
    const int* pos = (const int*)d_in[8];
    float* out = (float*)d_out;

    char* ws = (char*)d_ws;
    bf16_t* Abf  = (bf16_t*)(ws);                 // 32 MiB, reused as attn out
    bf16_t* B1T  = (bf16_t*)(ws + 33554432);      // 48 MiB (WqT|WkT|WvT), reused:
    bf16_t* Qo   = (bf16_t*)(ws + 33554432);      //   32 MiB
    bf16_t* Ko   = (bf16_t*)(ws + 67108864);      //   8 MiB
    bf16_t* Vt   = (bf16_t*)(ws + 75497472);      //   8 MiB
    bf16_t* WoT  = (bf16_t*)(ws + 83886080);      // 32 MiB
    bf16_t* qkv  = (bf16_t*)(ws + 117440512);     // 48 MiB
    bf16_t* attn = Abf;

    dim3 tb(32, 8);
    cast_kernel<<<16384, 256, 0, stream>>>(hidden, Abf, 4194304);
    transpose_cast<<<dim3(128, 128), tb, 0, stream>>>(Wq, B1T, 4096, 4096);
    transpose_cast<<<dim3(32, 128), tb, 0, stream>>>(Wk, B1T + (size_t)4096 * 4096, 4096, 1024);
    transpose_cast<<<dim3(32, 128), tb, 0, stream>>>(Wv, B1T + (size_t)5120 * 4096, 4096, 1024);
    transpose_cast<<<dim3(128, 128), tb, 0, stream>>>(Wo, WoT, 4096, 4096);

    // 256x128 tiles: grid (N/128, M/256)
    gemm256<bf16_t><<<dim3(48, 16), 512, 0, stream>>>(Abf, B1T, qkv, 4096, 6144, 4096);

    rope_kernel<<<dim3(10, 4096), 256, 0, stream>>>(qkv, pos, Qo, Ko);
    vtrans_kernel<<<dim3(32, 4, 32), tb, 0, stream>>>(qkv, Vt);

    attn_kernel<<<2048, 256, 0, stream>>>(Qo, Ko, Vt, attn);

    gemm256<float><<<dim3(32, 16), 512, 0, stream>>>(attn, WoT, out, 4096, 4096, 4096);
}

// Round 3
// 756.117 us; speedup vs baseline: 1.1925x; 1.0353x over previous
//
#include <hip/hip_runtime.h>
#include <cstdint>

typedef __bf16 bf16_t;
typedef __attribute__((ext_vector_type(8))) __bf16 bf16x8;
typedef __attribute__((ext_vector_type(4))) __bf16 bf16x4;
typedef __attribute__((ext_vector_type(4))) float f32x4;

typedef __attribute__((address_space(1))) void void_g;
typedef __attribute__((address_space(3))) void void_l;

#define GLDS16(gp, lp) __builtin_amdgcn_global_load_lds( \
    (void_g*)(uintptr_t)(gp), (void_l*)(uintptr_t)(lp), 16, 0, 0)

constexpr int Bc = 4, Sc = 1024, Hc = 32, KVHc = 8, HDc = 128, DMc = 4096;
constexpr int NQ = 6144;     // q|k|v concatenated width
constexpr int WINc = 512;

// ---------------- cast hidden fp32 -> bf16 (vectorized) ----------------
__global__ void cast_kernel(const float* __restrict__ in, bf16_t* __restrict__ out, int n4) {
    int i = blockIdx.x * blockDim.x + threadIdx.x;
    if (i >= n4) return;
    float4 v = reinterpret_cast<const float4*>(in)[i];
    bf16x4 o;
    o[0] = (bf16_t)v.x; o[1] = (bf16_t)v.y; o[2] = (bf16_t)v.z; o[3] = (bf16_t)v.w;
    reinterpret_cast<bf16x4*>(out)[i] = o;
}

// ---------------- cast+transpose: in fp32 [R][C] -> out bf16 [C][R] ----------------
__global__ void transpose_cast(const float* __restrict__ in, bf16_t* __restrict__ out,
                               int R, int C) {
    __shared__ float tile[32][33];
    int c0 = blockIdx.x * 32, r0 = blockIdx.y * 32;
    int tx = threadIdx.x, ty = threadIdx.y;   // (32,8)
    for (int i = 0; i < 32; i += 8)
        tile[ty + i][tx] = in[(size_t)(r0 + ty + i) * C + c0 + tx];
    __syncthreads();
    for (int i = 0; i < 32; i += 8)
        out[(size_t)(c0 + ty + i) * R + r0 + tx] = (bf16_t)tile[tx][ty + i];
}

// ---------------- bf16 MFMA GEMM: C[M][N] = A[M][K] * BT[N][K]^T ----------------
// 256x256 tile, BK=32, 8 waves (2M x 4N), per-wave 128x64 output (acc[8][4]).
// Quadruple-buffered LDS (4 x (16+16) KB = 128 KiB), staging THREE K-tiles ahead.
// Phase order (race-free, single barrier per phase):
//   vmcnt(8)  -- entering with 12 outstanding (tiles tt..tt+2), drains tile tt's 4
//   s_barrier -- all waves' tile-tt stages landed; all waves' reads of buf
//                (tt-1)&3 completed (their MFMAs consumed them pre-barrier)
//   stage tile tt+3 -> buf (tt+3)&3 == (tt-1)&3   (safe: issued after barrier)
//   12x ds_read_b128 from buf tt&3 ; 32x MFMA (setprio-wrapped)
// The wait covers loads issued 3 phases (~1500+ cy) earlier -> HBM latency hidden;
// vmcnt never drains to 0 until the peeled tail. Granule swizzle g ^= (row>>1)&3
// applied on BOTH stage-source address and LDS read (bank-conflict-free b128).
template <typename CT>
__global__ __launch_bounds__(512, 2) void gemm256(const bf16_t* __restrict__ A,
                                                  const bf16_t* __restrict__ BT,
                                                  CT* __restrict__ C,
                                                  int M, int N, int K) {
    __shared__ bf16_t As[4][256 * 32];   // [buf][row][col] 16 KB each
    __shared__ bf16_t Bs[4][256 * 32];

    const int t = threadIdx.x;
    const int lane = t & 63, w = t >> 6;
    const int wm = w >> 2, wn = w & 3;
    const int l15 = lane & 15, quad = lane >> 4;

    // group-major block remap: 8 consecutive M-tiles per N sweep (L2 locality)
    const int pid = blockIdx.y * gridDim.x + blockIdx.x;
    const int npn = gridDim.x, npm = gridDim.y;
    const int gsz = 8 * npn;
    const int grp = pid / gsz;
    const int first = grp * 8;
    const int gs = (npm - first) < 8 ? (npm - first) : 8;
    const int pm = first + (pid % gs);
    const int pn = (pid % gsz) / gs;
    const int mBase = pm * 256, nBase = pn * 256;

    // ---- staging (2 A-loads + 2 B-loads per thread per K-tile) ----
    // wave-load = 16 rows x 64B; lane l: row = w*16 + (l>>2), LDS granule l&3,
    // global granule (l&3) ^ (((l>>2)>>1)&3)  (inverse of read swizzle).
    const int srow = lane >> 2;                      // 0..15
    const int sg = (lane & 3) ^ ((srow >> 1) & 3);   // pre-swizzled source granule
    const int rL0 = w * 16 + srow;                   // rows 0..127
    const int rL1 = 128 + w * 16 + srow;             // rows 128..255
    const bf16_t* pA0 = A + (size_t)(mBase + rL0) * K + sg * 8;
    const bf16_t* pA1 = A + (size_t)(mBase + rL1) * K + sg * 8;
    const bf16_t* pB0 = BT + (size_t)(nBase + rL0) * K + sg * 8;
    const bf16_t* pB1 = BT + (size_t)(nBase + rL1) * K + sg * 8;
    const int dstL0 = w * 512;                       // LDS element offsets (wave-uniform)
    const int dstL1 = 4096 + w * 512;

    // ---- LDS read bases (matching swizzle) ----
    const int swz = (quad ^ ((l15 >> 1) & 3)) * 8;
    const int rdA = (wm * 128 + l15) * 32 + swz;
    const int rdB = (wn * 64 + l15) * 32 + swz;

    f32x4 acc[8][4] = {};
    const int NT = K >> 5;

    // prologue: stage tiles 0,1,2 (12 loads)
#pragma unroll
    for (int u = 0; u < 3; ++u) {
        const size_t kk = (size_t)u * 32;
        GLDS16(pA0 + kk, &As[u][dstL0]);
        GLDS16(pA1 + kk, &As[u][dstL1]);
        GLDS16(pB0 + kk, &Bs[u][dstL0]);
        GLDS16(pB1 + kk, &Bs[u][dstL1]);
    }

#define GBODY(VMC, DOSTAGE) do {                                              \
    const int buf = tt & 3;                                                   \
    asm volatile("s_waitcnt vmcnt(" #VMC ")" ::: "memory");                   \
    __builtin_amdgcn_s_barrier();                                             \
    __builtin_amdgcn_sched_barrier(0);                                        \
    if (DOSTAGE) {                                                            \
        const int ub = (tt + 3) & 3;                                          \
        const size_t kk = (size_t)(tt + 3) * 32;                              \
        GLDS16(pA0 + kk, &As[ub][dstL0]);                                     \
        GLDS16(pA1 + kk, &As[ub][dstL1]);                                     \
        GLDS16(pB0 + kk, &Bs[ub][dstL0]);                                     \
        GLDS16(pB1 + kk, &Bs[ub][dstL1]);                                     \
    }                                                                         \
    bf16x8 af[8], bv[4];                                                      \
    _Pragma("unroll")                                                         \
    for (int mf = 0; mf < 8; ++mf)                                            \
        af[mf] = *reinterpret_cast<const bf16x8*>(&As[buf][rdA + mf * 512]);  \
    _Pragma("unroll")                                                         \
    for (int nf = 0; nf < 4; ++nf)                                            \
        bv[nf] = *reinterpret_cast<const bf16x8*>(&Bs[buf][rdB + nf * 512]);  \
    __builtin_amdgcn_s_setprio(1);                                            \
    _Pragma("unroll")                                                         \
    for (int mf = 0; mf < 8; ++mf)                                            \
        _Pragma("unroll")                                                     \
        for (int nf = 0; nf < 4; ++nf)                                        \
            acc[mf][nf] = __builtin_amdgcn_mfma_f32_16x16x32_bf16(            \
                af[mf], bv[nf], acc[mf][nf], 0, 0, 0);                        \
    __builtin_amdgcn_s_setprio(0);                                            \
} while (0)

    for (int tt = 0; tt < NT - 3; ++tt) GBODY(8, true);
    { const int tt = NT - 3; GBODY(8, false); }
    { const int tt = NT - 2; GBODY(4, false); }
    { const int tt = NT - 1; GBODY(0, false); }
#undef GBODY

    // epilogue
#pragma unroll
    for (int mf = 0; mf < 8; ++mf) {
        const int row0 = mBase + wm * 128 + mf * 16 + quad * 4;
#pragma unroll
        for (int nf = 0; nf < 4; ++nf) {
            const int col = nBase + wn * 64 + nf * 16 + l15;
#pragma unroll
            for (int r = 0; r < 4; ++r)
                C[(size_t)(row0 + r) * N + col] = (CT)acc[mf][nf][r];
        }
    }
}

// ---------------- RoPE: qkv bf16 [4096][6144] -> Qo [4096][4096], Ko [4096][1024] ----------------
__global__ void rope_kernel(const bf16_t* __restrict__ qkv, const int* __restrict__ pos,
                            bf16_t* __restrict__ Qo, bf16_t* __restrict__ Ko) {
    int t = blockIdx.y;
    int hd = blockIdx.x * blockDim.x + threadIdx.x;  // 0..2559 (40 heads x 64 pairs)
    int head = hd >> 6, d = hd & 63;
    float p = (float)pos[t];
    float invf = exp2f(-(float)d * (19.931568569324174f / 64.0f));
    float ang = p * invf;
    float sn, cs;
    __sincosf(ang, &sn, &cs);
    const bf16_t* src; bf16_t* dst;
    if (head < 32) {
        src = qkv + (size_t)t * NQ + head * 128 + d;
        dst = Qo + (size_t)t * DMc + head * 128 + d;
    } else {
        int kh = head - 32;
        src = qkv + (size_t)t * NQ + 4096 + kh * 128 + d;
        dst = Ko + (size_t)t * (KVHc * HDc) + kh * 128 + d;
    }
    float x1 = (float)src[0], x2 = (float)src[64];
    dst[0]  = (bf16_t)(x1 * cs - x2 * sn);
    dst[64] = (bf16_t)(x2 * cs + x1 * sn);
}

// ---------------- V transpose: qkv v-part -> Vt [b*KVH][HD][S] ----------------
__global__ void vtrans_kernel(const bf16_t* __restrict__ qkv, bf16_t* __restrict__ Vt) {
    __shared__ bf16_t tile[32][33];
    int bh = blockIdx.z;               // b*8+kvh
    int b = bh >> 3, kvh = bh & 7;
    int s0 = blockIdx.x * 32, d0 = blockIdx.y * 32;
    int tx = threadIdx.x, ty = threadIdx.y;  // (32,8)
    for (int i = 0; i < 32; i += 8)
        tile[ty + i][tx] = qkv[(size_t)(b * Sc + s0 + ty + i) * NQ + 5120 + kvh * 128 + d0 + tx];
    __syncthreads();
    for (int i = 0; i < 32; i += 8)
        Vt[((size_t)bh * 128 + d0 + ty + i) * Sc + s0 + tx] = tile[tx][ty + i];
}

// ---------------- attention: 4 waves/block = 4 heads sharing a kvh group ----------------
// K/V tiles staged to LDS (double-buffered, XOR-swizzled), one barrier/step.
__global__ __launch_bounds__(256) void attn_kernel(const bf16_t* __restrict__ Q,
                                                   const bf16_t* __restrict__ Kk,
                                                   const bf16_t* __restrict__ Vt,
                                                   bf16_t* __restrict__ O) {
    __shared__ bf16_t Ks[2][32 * 128];
    __shared__ bf16_t Vs[2][128 * 32];
    __shared__ bf16_t Plds[4][16 * 32];
    const int bid = blockIdx.x;        // b*512 + kvh*64 + qt
    const int qt = bid & 63;
    const int kvh = (bid >> 6) & 7;
    const int b = bid >> 9;
    const int t = threadIdx.x;
    const int lane = t & 63, w = t >> 6;
    const int h = kvh * 4 + w;
    const int l15 = lane & 15, quad = lane >> 4;
    const int qb = qt * 16;

    // per-wave Q fragment (A-layout)
    bf16x8 qf[4];
    const bf16_t* qp = Q + (size_t)(b * Sc + qb + l15) * DMc + h * HDc + quad * 8;
#pragma unroll
    for (int c = 0; c < 4; c++) qf[c] = *reinterpret_cast<const bf16x8*>(qp + c * 32);

    // staging source offsets (per thread; two 16B granules per matrix)
    const int kr0 = t >> 4;                                 // rows 0..15 (second: +16)
    const int kc0 = (((t & 15) ^ (kr0 & 7)) * 8);
    const bf16_t* Kbase = Kk + (size_t)(b * Sc) * (KVHc * HDc) + kvh * HDc;
    const size_t kOff0 = (size_t)kr0 * (KVHc * HDc) + kc0;
    const size_t kOff1 = kOff0 + (size_t)16 * (KVHc * HDc);
    const int vd0 = t >> 2;                                 // d 0..63 (second: +64)
    const int vc0 = (((t & 3) ^ ((vd0 >> 1) & 3)) * 8);
    const bf16_t* Vbase = Vt + (size_t)(b * KVHc + kvh) * HDc * Sc;
    const size_t vOff0 = (size_t)vd0 * Sc + vc0;
    const size_t vOff1 = vOff0 + (size_t)64 * Sc;

    f32x4 oacc[8] = {};
    float m_r[4], l_r[4];
#pragma unroll
    for (int r = 0; r < 4; r++) { m_r[r] = -1e30f; l_r[r] = 0.f; }

    const int swl = (l15 >> 1) & 3;    // V/P read-granule swizzle
    const int swk = l15 & 7;           // K read-granule swizzle

    int lo = qb - (WINc - 1); if (lo < 0) lo = 0;
    const int kv_lo = lo & ~31;
    const int nsteps = (qb + 16 - kv_lo + 31) / 32;

    // prologue stage into buf 0
    {
        const bf16_t* ks = Kbase + (size_t)kv_lo * (KVHc * HDc);
        GLDS16(ks + kOff0, &Ks[0][w * 512]);
        GLDS16(ks + kOff1, &Ks[0][2048 + w * 512]);
        const bf16_t* vs = Vbase + kv_lo;
        GLDS16(vs + vOff0, &Vs[0][w * 512]);
        GLDS16(vs + vOff1, &Vs[0][2048 + w * 512]);
    }

    int buf = 0;
    for (int s = 0; s < nsteps; s++) {
        const int kv = kv_lo + s * 32;
        __syncthreads();   // staging of buf complete; prior reads of buf^1 done
        if (s + 1 < nsteps) {
            const int nb = buf ^ 1;
            const bf16_t* ks = Kbase + (size_t)(kv + 32) * (KVHc * HDc);
            GLDS16(ks + kOff0, &Ks[nb][w * 512]);
            GLDS16(ks + kOff1, &Ks[nb][2048 + w * 512]);
            const bf16_t* vs = Vbase + kv + 32;
            GLDS16(vs + vOff0, &Vs[nb][w * 512]);
            GLDS16(vs + vOff1, &Vs[nb][2048 + w * 512]);
        }
        // QK^T from LDS
        f32x4 s0 = {}, s1 = {};
#pragma unroll
        for (int c = 0; c < 4; c++) {
            bf16x8 kf = *reinterpret_cast<const bf16x8*>(
                &Ks[buf][l15 * 128 + (((c * 4 + quad) ^ swk) * 8)]);
            s0 = __builtin_amdgcn_mfma_f32_16x16x32_bf16(qf[c], kf, s0, 0, 0, 0);
        }
#pragma unroll
        for (int c = 0; c < 4; c++) {
            bf16x8 kf = *reinterpret_cast<const bf16x8*>(
                &Ks[buf][(16 + l15) * 128 + (((c * 4 + quad) ^ swk) * 8)]);
            s1 = __builtin_amdgcn_mfma_f32_16x16x32_bf16(qf[c], kf, s1, 0, 0, 0);
        }
        const float scale = 0.08838834764831845f;  // 1/sqrt(128)
        const bool interior = (kv + 31 <= qb) && (kv >= qb - 496);
        float p0[4], p1[4], alpha[4];
#pragma unroll
        for (int r = 0; r < 4; r++) {
            float v0, v1;
            if (interior) {
                v0 = s0[r] * scale; v1 = s1[r] * scale;
            } else {
                int i = qb + quad * 4 + r;
                int j0 = kv + l15, j1 = j0 + 16;
                v0 = (j0 <= i && j0 > i - WINc) ? s0[r] * scale : -1e30f;
                v1 = (j1 <= i && j1 > i - WINc) ? s1[r] * scale : -1e30f;
            }
            float mx = fmaxf(v0, v1);
            mx = fmaxf(mx, __shfl_xor(mx, 1));
            mx = fmaxf(mx, __shfl_xor(mx, 2));
            mx = fmaxf(mx, __shfl_xor(mx, 4));
            mx = fmaxf(mx, __shfl_xor(mx, 8));
            float mnew = fmaxf(m_r[r], mx);
            alpha[r] = __expf(m_r[r] - mnew);
            m_r[r] = mnew;
            p0[r] = __expf(v0 - mnew);
            p1[r] = __expf(v1 - mnew);
            float rs = p0[r] + p1[r];
            rs += __shfl_xor(rs, 1);
            rs += __shfl_xor(rs, 2);
            rs += __shfl_xor(rs, 4);
            rs += __shfl_xor(rs, 8);
            l_r[r] = l_r[r] * alpha[r] + rs;
        }
#pragma unroll
        for (int c = 0; c < 8; c++)
#pragma unroll
            for (int r = 0; r < 4; r++)
                oacc[c][r] *= alpha[r];
        // P: C-layout -> LDS (swizzled) -> A-layout fragment (wave-local ordering
        // via compiler-inserted lgkmcnt; no barrier so prefetch stays in flight)
#pragma unroll
        for (int r = 0; r < 4; r++) {
            int row = quad * 4 + r;
            int sw = (row >> 1) & 3;
            int g0 = l15 >> 3, g1 = 2 + (l15 >> 3);
            Plds[w][row * 32 + (((g0 ^ sw) << 3) | (l15 & 7))] = (bf16_t)p0[r];
            Plds[w][row * 32 + (((g1 ^ sw) << 3) | (l15 & 7))] = (bf16_t)p1[r];
        }
        bf16x8 pf = *reinterpret_cast<const bf16x8*>(&Plds[w][l15 * 32 + ((quad ^ swl) * 8)]);
#pragma unroll
        for (int c = 0; c < 8; c++) {
            bf16x8 vf = *reinterpret_cast<const bf16x8*>(
                &Vs[buf][(c * 16 + l15) * 32 + ((quad ^ swl) * 8)]);
            oacc[c] = __builtin_amdgcn_mfma_f32_16x16x32_bf16(pf, vf, oacc[c], 0, 0, 0);
        }
        buf ^= 1;
    }
    bf16_t* op = O + (size_t)(b * Sc + qb) * DMc + h * HDc;
#pragma unroll
    for (int r = 0; r < 4; r++) {
        float inv = 1.0f / l_r[r];
        int row = quad * 4 + r;
#pragma unroll
        for (int c = 0; c < 8; c++)
            op[(size_t)row * DMc + c * 16 + l15] = (bf16_t)(oacc[c][r] * inv);
    }
}

extern "C" void kernel_launch(void* const* d_in, const int* in_sizes, int n_in,
                              void* d_out, int out_size, void* d_ws, size_t ws_size,
                              hipStream_t stream) {
    const float* hidden = (const float*)d_in[0];
    const float* Wq = (const float*)d_in[1];
    const float* Wk = (const float*)d_in[2];
    const float* Wv = (const float*)d_in[3];
    const float* Wo = (const float*)d_in[4];
    const int* pos = (const int*)d_in[8];
    float* out = (float*)d_out;

    char* ws = (char*)d_ws;
    bf16_t* Abf  = (bf16_t*)(ws);                 // 32 MiB, reused as attn out
    bf16_t* B1T  = (bf16_t*)(ws + 33554432);      // 48 MiB (WqT|WkT|WvT), reused:
    bf16_t* Qo   = (bf16_t*)(ws + 33554432);      //   32 MiB
    bf16_t* Ko   = (bf16_t*)(ws + 67108864);      //   8 MiB
    bf16_t* Vt   = (bf16_t*)(ws + 75497472);      //   8 MiB
    bf16_t* WoT  = (bf16_t*)(ws + 83886080);      // 32 MiB
    bf16_t* qkv  = (bf16_t*)(ws + 117440512);     // 48 MiB
    bf16_t* attn = Abf;

    dim3 tb(32, 8);
    cast_kernel<<<16384, 256, 0, stream>>>(hidden, Abf, 4194304);
    transpose_cast<<<dim3(128, 128), tb, 0, stream>>>(Wq, B1T, 4096, 4096);
    transpose_cast<<<dim3(32, 128), tb, 0, stream>>>(Wk, B1T + (size_t)4096 * 4096, 4096, 1024);
    transpose_cast<<<dim3(32, 128), tb, 0, stream>>>(Wv, B1T + (size_t)5120 * 4096, 4096, 1024);
    transpose_cast<<<dim3(128, 128), tb, 0, stream>>>(Wo, WoT, 4096, 4096);

    // 256x256 tiles: grid (N/256, M/256)
    gemm256<bf16_t><<<dim3(24, 16), 512, 0, stream>>>(Abf, B1T, qkv, 4096, 6144, 4096);

    rope_kernel<<<dim3(10, 4096), 256, 0, stream>>>(qkv, pos, Qo, Ko);
    vtrans_kernel<<<dim3(32, 4, 32), tb, 0, stream>>>(qkv, Vt);

    attn_kernel<<<2048, 256, 0, stream>>>(Qo, Ko, Vt, attn);

    gemm256<float><<<dim3(16, 16), 512, 0, stream>>>(attn, WoT, out, 4096, 4096, 4096);
}

// Round 4
// 752.404 us; speedup vs baseline: 1.1984x; 1.0049x over previous
//
#include <hip/hip_runtime.h>
#include <cstdint>

typedef __bf16 bf16_t;
typedef __attribute__((ext_vector_type(8))) __bf16 bf16x8;
typedef __attribute__((ext_vector_type(4))) __bf16 bf16x4;
typedef __attribute__((ext_vector_type(4))) float f32x4;

typedef __attribute__((address_space(1))) void void_g;
typedef __attribute__((address_space(3))) void void_l;

#define GLDS16(gp, lp) __builtin_amdgcn_global_load_lds( \
    (void_g*)(uintptr_t)(gp), (void_l*)(uintptr_t)(lp), 16, 0, 0)

constexpr int Bc = 4, Sc = 1024, Hc = 32, KVHc = 8, HDc = 128, DMc = 4096;
constexpr int NQ = 6144;     // q|k|v concatenated width
constexpr int WINc = 512;

// ---------------- cast hidden fp32 -> bf16 (vectorized) ----------------
__global__ void cast_kernel(const float* __restrict__ in, bf16_t* __restrict__ out, int n4) {
    int i = blockIdx.x * blockDim.x + threadIdx.x;
    if (i >= n4) return;
    float4 v = reinterpret_cast<const float4*>(in)[i];
    bf16x4 o;
    o[0] = (bf16_t)v.x; o[1] = (bf16_t)v.y; o[2] = (bf16_t)v.z; o[3] = (bf16_t)v.w;
    reinterpret_cast<bf16x4*>(out)[i] = o;
}

// ---------------- cast+transpose: in fp32 [R][C] -> out bf16 [C][R] ----------------
__global__ void transpose_cast(const float* __restrict__ in, bf16_t* __restrict__ out,
                               int R, int C) {
    __shared__ float tile[32][33];
    int c0 = blockIdx.x * 32, r0 = blockIdx.y * 32;
    int tx = threadIdx.x, ty = threadIdx.y;   // (32,8)
    for (int i = 0; i < 32; i += 8)
        tile[ty + i][tx] = in[(size_t)(r0 + ty + i) * C + c0 + tx];
    __syncthreads();
    for (int i = 0; i < 32; i += 8)
        out[(size_t)(c0 + ty + i) * R + r0 + tx] = (bf16_t)tile[tx][ty + i];
}

// ---------------- bf16 MFMA GEMM: C[M][N] = A[M][K] * BT[N][K]^T ----------------
// 256x256 tile, BK=32, 8 waves (2M x 4N), per-wave 128x64 output (acc[8][4]).
// 4-buffer LDS ring, staging 3 K-tiles ahead; REGISTER PREFETCH one K-tile ahead:
// iteration t runs MFMAs on fragments R(t) loaded at the END of iteration t-1,
// then issues R(t+1)'s 12 ds_read_b128 (they retire under the next barrier /
// other wave's MFMA cluster -> LDS latency off the critical path).
// Gates: vmcnt(4) at each barrier guarantees tiles t AND t+1 are in LDS (loads
// were issued 2-3 phases = >2500cy earlier). Stage of t+3 targets buf (t-1)&3
// whose reads completed at iter t-1's lgkmcnt(0). Tail peels vmcnt(0)x2.
// Granule swizzle g ^= (row>>1)&3 on BOTH stage-source and LDS read.
template <typename CT>
__global__ __launch_bounds__(512, 2) void gemm256(const bf16_t* __restrict__ A,
                                                  const bf16_t* __restrict__ BT,
                                                  CT* __restrict__ C,
                                                  int M, int N, int K) {
    __shared__ bf16_t As[4][256 * 32];   // [buf][row][col] 16 KB each
    __shared__ bf16_t Bs[4][256 * 32];

    const int t = threadIdx.x;
    const int lane = t & 63, w = t >> 6;
    const int wm = w >> 2, wn = w & 3;
    const int l15 = lane & 15, quad = lane >> 4;

    // group-major block remap: 8 consecutive M-tiles per N sweep (L2 locality)
    const int pid = blockIdx.y * gridDim.x + blockIdx.x;
    const int npn = gridDim.x, npm = gridDim.y;
    const int gsz = 8 * npn;
    const int grp = pid / gsz;
    const int first = grp * 8;
    const int gs = (npm - first) < 8 ? (npm - first) : 8;
    const int pm = first + (pid % gs);
    const int pn = (pid % gsz) / gs;
    const int mBase = pm * 256, nBase = pn * 256;

    // ---- staging (2 A-loads + 2 B-loads per thread per K-tile) ----
    const int srow = lane >> 2;                      // 0..15
    const int sg = (lane & 3) ^ ((srow >> 1) & 3);   // pre-swizzled source granule
    const int rL0 = w * 16 + srow;                   // rows 0..127
    const int rL1 = 128 + w * 16 + srow;             // rows 128..255
    const bf16_t* pA0 = A + (size_t)(mBase + rL0) * K + sg * 8;
    const bf16_t* pA1 = A + (size_t)(mBase + rL1) * K + sg * 8;
    const bf16_t* pB0 = BT + (size_t)(nBase + rL0) * K + sg * 8;
    const bf16_t* pB1 = BT + (size_t)(nBase + rL1) * K + sg * 8;
    const int dstL0 = w * 512;                       // LDS element offsets (wave-uniform)
    const int dstL1 = 4096 + w * 512;

    // ---- LDS read bases (matching swizzle) ----
    const int swz = (quad ^ ((l15 >> 1) & 3)) * 8;
    const int rdA = (wm * 128 + l15) * 32 + swz;
    const int rdB = (wn * 64 + l15) * 32 + swz;

    f32x4 acc[8][4] = {};
    bf16x8 af[8], bv[4];
    const int NT = K >> 5;

    // prologue: stage tiles 0,1,2 (12 loads)
#pragma unroll
    for (int u = 0; u < 3; ++u) {
        const size_t kk = (size_t)u * 32;
        GLDS16(pA0 + kk, &As[u][dstL0]);
        GLDS16(pA1 + kk, &As[u][dstL1]);
        GLDS16(pB0 + kk, &Bs[u][dstL0]);
        GLDS16(pB1 + kk, &Bs[u][dstL1]);
    }

#define READF(tv) do {                                                        \
    const int rb = (tv) & 3;                                                  \
    _Pragma("unroll")                                                         \
    for (int mf = 0; mf < 8; ++mf)                                            \
        af[mf] = *reinterpret_cast<const bf16x8*>(&As[rb][rdA + mf * 512]);   \
    _Pragma("unroll")                                                         \
    for (int nf = 0; nf < 4; ++nf)                                            \
        bv[nf] = *reinterpret_cast<const bf16x8*>(&Bs[rb][rdB + nf * 512]);   \
} while (0)

#define ITER(tv, VMC, DOSTAGE, READNEXT) do {                                 \
    asm volatile("s_waitcnt vmcnt(" #VMC ")" ::: "memory");                   \
    __builtin_amdgcn_s_barrier();                                             \
    if (DOSTAGE) {                                                            \
        const int ub = ((tv) + 3) & 3;                                        \
        const size_t kk = (size_t)((tv) + 3) * 32;                            \
        GLDS16(pA0 + kk, &As[ub][dstL0]);                                     \
        GLDS16(pA1 + kk, &As[ub][dstL1]);                                     \
        GLDS16(pB0 + kk, &Bs[ub][dstL0]);                                     \
        GLDS16(pB1 + kk, &Bs[ub][dstL1]);                                     \
    }                                                                         \
    asm volatile("s_waitcnt lgkmcnt(0)" ::: "memory");                        \
    __builtin_amdgcn_sched_barrier(0);                                        \
    __builtin_amdgcn_s_setprio(1);                                            \
    _Pragma("unroll")                                                         \
    for (int mf = 0; mf < 8; ++mf)                                            \
        _Pragma("unroll")                                                     \
        for (int nf = 0; nf < 4; ++nf)                                        \
            acc[mf][nf] = __builtin_amdgcn_mfma_f32_16x16x32_bf16(            \
                af[mf], bv[nf], acc[mf][nf], 0, 0, 0);                        \
    __builtin_amdgcn_s_setprio(0);                                            \
    if (READNEXT) READF((tv) + 1);                                            \
} while (0)

    // R(0): tile 0 guaranteed in LDS after vmcnt(8) (drains tile 0's 4 loads)
    asm volatile("s_waitcnt vmcnt(8)" ::: "memory");
    __builtin_amdgcn_s_barrier();
    READF(0);

    for (int tt = 0; tt < NT - 3; ++tt) ITER(tt, 4, true, true);
    { const int tt = NT - 3; ITER(tt, 4, false, true); }
    { const int tt = NT - 2; ITER(tt, 0, false, true); }
    { const int tt = NT - 1; ITER(tt, 0, false, false); }
#undef ITER
#undef READF

    // epilogue
#pragma unroll
    for (int mf = 0; mf < 8; ++mf) {
        const int row0 = mBase + wm * 128 + mf * 16 + quad * 4;
#pragma unroll
        for (int nf = 0; nf < 4; ++nf) {
            const int col = nBase + wn * 64 + nf * 16 + l15;
#pragma unroll
            for (int r = 0; r < 4; ++r)
                C[(size_t)(row0 + r) * N + col] = (CT)acc[mf][nf][r];
        }
    }
}

// ---------------- RoPE: qkv bf16 [4096][6144] -> Qo [4096][4096], Ko [4096][1024] ----------------
__global__ void rope_kernel(const bf16_t* __restrict__ qkv, const int* __restrict__ pos,
                            bf16_t* __restrict__ Qo, bf16_t* __restrict__ Ko) {
    int t = blockIdx.y;
    int hd = blockIdx.x * blockDim.x + threadIdx.x;  // 0..2559 (40 heads x 64 pairs)
    int head = hd >> 6, d = hd & 63;
    float p = (float)pos[t];
    float invf = exp2f(-(float)d * (19.931568569324174f / 64.0f));
    float ang = p * invf;
    float sn, cs;
    __sincosf(ang, &sn, &cs);
    const bf16_t* src; bf16_t* dst;
    if (head < 32) {
        src = qkv + (size_t)t * NQ + head * 128 + d;
        dst = Qo + (size_t)t * DMc + head * 128 + d;
    } else {
        int kh = head - 32;
        src = qkv + (size_t)t * NQ + 4096 + kh * 128 + d;
        dst = Ko + (size_t)t * (KVHc * HDc) + kh * 128 + d;
    }
    float x1 = (float)src[0], x2 = (float)src[64];
    dst[0]  = (bf16_t)(x1 * cs - x2 * sn);
    dst[64] = (bf16_t)(x2 * cs + x1 * sn);
}

// ---------------- V transpose: qkv v-part -> Vt [b*KVH][HD][S] ----------------
__global__ void vtrans_kernel(const bf16_t* __restrict__ qkv, bf16_t* __restrict__ Vt) {
    __shared__ bf16_t tile[32][33];
    int bh = blockIdx.z;               // b*8+kvh
    int b = bh >> 3, kvh = bh & 7;
    int s0 = blockIdx.x * 32, d0 = blockIdx.y * 32;
    int tx = threadIdx.x, ty = threadIdx.y;  // (32,8)
    for (int i = 0; i < 32; i += 8)
        tile[ty + i][tx] = qkv[(size_t)(b * Sc + s0 + ty + i) * NQ + 5120 + kvh * 128 + d0 + tx];
    __syncthreads();
    for (int i = 0; i < 32; i += 8)
        Vt[((size_t)bh * 128 + d0 + ty + i) * Sc + s0 + tx] = tile[tx][ty + i];
}

// ---------------- attention: 4 waves/block = 4 heads sharing a kvh group ----------------
// K/V tiles staged to LDS (double-buffered, XOR-swizzled), one barrier/step.
__global__ __launch_bounds__(256) void attn_kernel(const bf16_t* __restrict__ Q,
                                                   const bf16_t* __restrict__ Kk,
                                                   const bf16_t* __restrict__ Vt,
                                                   bf16_t* __restrict__ O) {
    __shared__ bf16_t Ks[2][32 * 128];
    __shared__ bf16_t Vs[2][128 * 32];
    __shared__ bf16_t Plds[4][16 * 32];
    const int bid = blockIdx.x;        // b*512 + kvh*64 + qt
    const int qt = bid & 63;
    const int kvh = (bid >> 6) & 7;
    const int b = bid >> 9;
    const int t = threadIdx.x;
    const int lane = t & 63, w = t >> 6;
    const int h = kvh * 4 + w;
    const int l15 = lane & 15, quad = lane >> 4;
    const int qb = qt * 16;

    // per-wave Q fragment (A-layout)
    bf16x8 qf[4];
    const bf16_t* qp = Q + (size_t)(b * Sc + qb + l15) * DMc + h * HDc + quad * 8;
#pragma unroll
    for (int c = 0; c < 4; c++) qf[c] = *reinterpret_cast<const bf16x8*>(qp + c * 32);

    // staging source offsets (per thread; two 16B granules per matrix)
    const int kr0 = t >> 4;                                 // rows 0..15 (second: +16)
    const int kc0 = (((t & 15) ^ (kr0 & 7)) * 8);
    const bf16_t* Kbase = Kk + (size_t)(b * Sc) * (KVHc * HDc) + kvh * HDc;
    const size_t kOff0 = (size_t)kr0 * (KVHc * HDc) + kc0;
    const size_t kOff1 = kOff0 + (size_t)16 * (KVHc * HDc);
    const int vd0 = t >> 2;                                 // d 0..63 (second: +64)
    const int vc0 = (((t & 3) ^ ((vd0 >> 1) & 3)) * 8);
    const bf16_t* Vbase = Vt + (size_t)(b * KVHc + kvh) * HDc * Sc;
    const size_t vOff0 = (size_t)vd0 * Sc + vc0;
    const size_t vOff1 = vOff0 + (size_t)64 * Sc;

    f32x4 oacc[8] = {};
    float m_r[4], l_r[4];
#pragma unroll
    for (int r = 0; r < 4; r++) { m_r[r] = -1e30f; l_r[r] = 0.f; }

    const int swl = (l15 >> 1) & 3;    // V/P read-granule swizzle
    const int swk = l15 & 7;           // K read-granule swizzle

    int lo = qb - (WINc - 1); if (lo < 0) lo = 0;
    const int kv_lo = lo & ~31;
    const int nsteps = (qb + 16 - kv_lo + 31) / 32;

    // prologue stage into buf 0
    {
        const bf16_t* ks = Kbase + (size_t)kv_lo * (KVHc * HDc);
        GLDS16(ks + kOff0, &Ks[0][w * 512]);
        GLDS16(ks + kOff1, &Ks[0][2048 + w * 512]);
        const bf16_t* vs = Vbase + kv_lo;
        GLDS16(vs + vOff0, &Vs[0][w * 512]);
        GLDS16(vs + vOff1, &Vs[0][2048 + w * 512]);
    }

    int buf = 0;
    for (int s = 0; s < nsteps; s++) {
        const int kv = kv_lo + s * 32;
        __syncthreads();   // staging of buf complete; prior reads of buf^1 done
        if (s + 1 < nsteps) {
            const int nb = buf ^ 1;
            const bf16_t* ks = Kbase + (size_t)(kv + 32) * (KVHc * HDc);
            GLDS16(ks + kOff0, &Ks[nb][w * 512]);
            GLDS16(ks + kOff1, &Ks[nb][2048 + w * 512]);
            const bf16_t* vs = Vbase + kv + 32;
            GLDS16(vs + vOff0, &Vs[nb][w * 512]);
            GLDS16(vs + vOff1, &Vs[nb][2048 + w * 512]);
        }
        // QK^T from LDS
        f32x4 s0 = {}, s1 = {};
#pragma unroll
        for (int c = 0; c < 4; c++) {
            bf16x8 kf = *reinterpret_cast<const bf16x8*>(
                &Ks[buf][l15 * 128 + (((c * 4 + quad) ^ swk) * 8)]);
            s0 = __builtin_amdgcn_mfma_f32_16x16x32_bf16(qf[c], kf, s0, 0, 0, 0);
        }
#pragma unroll
        for (int c = 0; c < 4; c++) {
            bf16x8 kf = *reinterpret_cast<const bf16x8*>(
                &Ks[buf][(16 + l15) * 128 + (((c * 4 + quad) ^ swk) * 8)]);
            s1 = __builtin_amdgcn_mfma_f32_16x16x32_bf16(qf[c], kf, s1, 0, 0, 0);
        }
        const float scale = 0.08838834764831845f;  // 1/sqrt(128)
        const bool interior = (kv + 31 <= qb) && (kv >= qb - 496);
        float p0[4], p1[4], alpha[4];
#pragma unroll
        for (int r = 0; r < 4; r++) {
            float v0, v1;
            if (interior) {
                v0 = s0[r] * scale; v1 = s1[r] * scale;
            } else {
                int i = qb + quad * 4 + r;
                int j0 = kv + l15, j1 = j0 + 16;
                v0 = (j0 <= i && j0 > i - WINc) ? s0[r] * scale : -1e30f;
                v1 = (j1 <= i && j1 > i - WINc) ? s1[r] * scale : -1e30f;
            }
            float mx = fmaxf(v0, v1);
            mx = fmaxf(mx, __shfl_xor(mx, 1));
            mx = fmaxf(mx, __shfl_xor(mx, 2));
            mx = fmaxf(mx, __shfl_xor(mx, 4));
            mx = fmaxf(mx, __shfl_xor(mx, 8));
            float mnew = fmaxf(m_r[r], mx);
            alpha[r] = __expf(m_r[r] - mnew);
            m_r[r] = mnew;
            p0[r] = __expf(v0 - mnew);
            p1[r] = __expf(v1 - mnew);
            float rs = p0[r] + p1[r];
            rs += __shfl_xor(rs, 1);
            rs += __shfl_xor(rs, 2);
            rs += __shfl_xor(rs, 4);
            rs += __shfl_xor(rs, 8);
            l_r[r] = l_r[r] * alpha[r] + rs;
        }
#pragma unroll
        for (int c = 0; c < 8; c++)
#pragma unroll
            for (int r = 0; r < 4; r++)
                oacc[c][r] *= alpha[r];
        // P: C-layout -> LDS (swizzled) -> A-layout fragment (wave-local ordering
        // via compiler-inserted lgkmcnt; no barrier so prefetch stays in flight)
#pragma unroll
        for (int r = 0; r < 4; r++) {
            int row = quad * 4 + r;
            int sw = (row >> 1) & 3;
            int g0 = l15 >> 3, g1 = 2 + (l15 >> 3);
            Plds[w][row * 32 + (((g0 ^ sw) << 3) | (l15 & 7))] = (bf16_t)p0[r];
            Plds[w][row * 32 + (((g1 ^ sw) << 3) | (l15 & 7))] = (bf16_t)p1[r];
        }
        bf16x8 pf = *reinterpret_cast<const bf16x8*>(&Plds[w][l15 * 32 + ((quad ^ swl) * 8)]);
#pragma unroll
        for (int c = 0; c < 8; c++) {
            bf16x8 vf = *reinterpret_cast<const bf16x8*>(
                &Vs[buf][(c * 16 + l15) * 32 + ((quad ^ swl) * 8)]);
            oacc[c] = __builtin_amdgcn_mfma_f32_16x16x32_bf16(pf, vf, oacc[c], 0, 0, 0);
        }
        buf ^= 1;
    }
    bf16_t* op = O + (size_t)(b * Sc + qb) * DMc + h * HDc;
#pragma unroll
    for (int r = 0; r < 4; r++) {
        float inv = 1.0f / l_r[r];
        int row = quad * 4 + r;
#pragma unroll
        for (int c = 0; c < 8; c++)
            op[(size_t)row * DMc + c * 16 + l15] = (bf16_t)(oacc[c][r] * inv);
    }
}

extern "C" void kernel_launch(void* const* d_in, const int* in_sizes, int n_in,
                              void* d_out, int out_size, void* d_ws, size_t ws_size,
                              hipStream_t stream) {
    const float* hidden = (const float*)d_in[0];
    const float* Wq = (const float*)d_in[1];
    const float* Wk = (const float*)d_in[2];
    const float* Wv = (const float*)d_in[3];
    const float* Wo = (const float*)d_in[4];
    const int* pos = (const int*)d_in[8];
    float* out = (float*)d_out;

    char* ws = (char*)d_ws;
    bf16_t* Abf  = (bf16_t*)(ws);                 // 32 MiB, reused as attn out
    bf16_t* B1T  = (bf16_t*)(ws + 33554432);      // 48 MiB (WqT|WkT|WvT), reused:
    bf16_t* Qo   = (bf16_t*)(ws + 33554432);      //   32 MiB
    bf16_t* Ko   = (bf16_t*)(ws + 67108864);      //   8 MiB
    bf16_t* Vt   = (bf16_t*)(ws + 75497472);      //   8 MiB
    bf16_t* WoT  = (bf16_t*)(ws + 83886080);      // 32 MiB
    bf16_t* qkv  = (bf16_t*)(ws + 117440512);     // 48 MiB
    bf16_t* attn = Abf;

    dim3 tb(32, 8);
    cast_kernel<<<16384, 256, 0, stream>>>(hidden, Abf, 4194304);
    transpose_cast<<<dim3(128, 128), tb, 0, stream>>>(Wq, B1T, 4096, 4096);
    transpose_cast<<<dim3(32, 128), tb, 0, stream>>>(Wk, B1T + (size_t)4096 * 4096, 4096, 1024);
    transpose_cast<<<dim3(32, 128), tb, 0, stream>>>(Wv, B1T + (size_t)5120 * 4096, 4096, 1024);
    transpose_cast<<<dim3(128, 128), tb, 0, stream>>>(Wo, WoT, 4096, 4096);

    // 256x256 tiles: grid (N/256, M/256)
    gemm256<bf16_t><<<dim3(24, 16), 512, 0, stream>>>(Abf, B1T, qkv, 4096, 6144, 4096);

    rope_kernel<<<dim3(10, 4096), 256, 0, stream>>>(qkv, pos, Qo, Ko);
    vtrans_kernel<<<dim3(32, 4, 32), tb, 0, stream>>>(qkv, Vt);

    attn_kernel<<<2048, 256, 0, stream>>>(Qo, Ko, Vt, attn);

    gemm256<float><<<dim3(16, 16), 512, 0, stream>>>(attn, WoT, out, 4096, 4096, 4096);
}